// Round 1
// baseline (472.088 us; speedup 1.0000x reference)
//
#include <hip/hip_runtime.h>
#include <math.h>

#define NK 512                      // N_EMB
#define DIMV 64
#define NPTS (32*64*64)             // 131072 points
#define NELEM (32*64*64*64)         // 8388608 elements of z
#define WT_STRIDE 132               // 128 codes + pad, keeps 16B alignment (132*4=528=33*16)

// flat d_out offsets (return order: loss, z_q, perplexity, encodings, codebook)
#define OFF_LOSS 0
#define OFF_ZQ   1
#define OFF_PERP (1 + NELEM)                       // 8388609
#define OFF_ENC  (2 + NELEM)                       // 8388610
#define OFF_CB   (2 + NELEM + (size_t)NPTS * NK)   // 75497474

__global__ __launch_bounds__(256) void vq_main(const float* __restrict__ zg,
                                               const float* __restrict__ wg,
                                               float* __restrict__ out,
                                               int* __restrict__ hist,
                                               double* __restrict__ lossAcc) {
    const int t = threadIdx.x;
    const int blk = blockIdx.x;          // 2048 blocks = (b,h)
    const int b = blk >> 6;
    const int h = blk & 63;

    __shared__ __align__(16) float zt[64 * 64];          // zt[d][p], p contiguous
    __shared__ __align__(16) float wt[64 * WT_STRIDE];   // wt[d][k] chunk; overlaid later
    __shared__ float aRow[64];
    __shared__ float bnd[128];
    __shared__ int   idxs[64];
    __shared__ float rsum[256];

    // overlays into wt region (valid after last chunk's compute + a barrier)
    float* zqt  = wt;                    // [64][64] gathered winner rows, d-major
    float* redv = wt + 4096;             // [16][66]
    int*   redi = (int*)(wt + 4096 + 16 * 66);  // [16][64]

    // ---- stage z tile: zt[c][w] = z[b,c,h,w] (coalesced reads, 2-way LDS free) ----
    {
        const int w = t & 63;
        const int c0 = t >> 6;
        const size_t base = (size_t)b * 262144 + (size_t)h * 64;
        #pragma unroll
        for (int c = c0; c < 64; c += 4)
            zt[c * 64 + w] = zg[base + (size_t)c * 4096 + w];
    }
    __syncthreads();

    // ---- a_p = sum_d z^2 (sequential d, explicit mul+add to match elementwise+reduce) ----
    if (t < 64) {
        float s = 0.f;
        for (int d = 0; d < 64; ++d) {
            float v = zt[d * 64 + t];
            s = __fadd_rn(s, __fmul_rn(v, v));
        }
        aRow[t] = s;
    }
    __syncthreads();

    const int tx = t & 15;               // code sub-tile
    const int ty = t >> 4;               // point sub-tile
    const int ty4 = ty * 4;
    const int tx8 = tx * 8;

    float av[4];
    #pragma unroll
    for (int i = 0; i < 4; ++i) av[i] = aRow[ty4 + i];

    float best[4];
    int bidx[4];
    #pragma unroll
    for (int i = 0; i < 4; ++i) { best[i] = INFINITY; bidx[i] = 0; }

    for (int chunk = 0; chunk < 4; ++chunk) {
        // stage codebook chunk transposed: wt[d][kk] = w[(chunk*128+kk)*64 + d]
        {
            const int d = t & 63, kk0 = t >> 6;
            #pragma unroll
            for (int kk = kk0; kk < 128; kk += 4)
                wt[d * WT_STRIDE + kk] = wg[((size_t)(chunk * 128 + kk)) * 64 + d];
        }
        __syncthreads();

        // b_k for this chunk (sequential d, mul+add)
        if (t < 128) {
            float s = 0.f;
            for (int d = 0; d < 64; ++d) {
                float v = wt[d * WT_STRIDE + t];
                s = __fadd_rn(s, __fmul_rn(v, v));
            }
            bnd[t] = s;
        }
        __syncthreads();

        // ---- register-tiled dot products: 4 points x 8 codes ----
        float acc[4][8];
        #pragma unroll
        for (int i = 0; i < 4; ++i)
            #pragma unroll
            for (int j = 0; j < 8; ++j) acc[i][j] = 0.f;

        const float* ztp = zt + ty4;
        const float* wtp = wt + tx8;
        #pragma unroll 4
        for (int d = 0; d < 64; ++d) {
            const float4 zv = *(const float4*)(ztp + d * 64);
            const float4 w0 = *(const float4*)(wtp + d * WT_STRIDE);
            const float4 w1 = *(const float4*)(wtp + d * WT_STRIDE + 4);
            const float zr[4] = {zv.x, zv.y, zv.z, zv.w};
            const float wr[8] = {w0.x, w0.y, w0.z, w0.w, w1.x, w1.y, w1.z, w1.w};
            #pragma unroll
            for (int i = 0; i < 4; ++i)
                #pragma unroll
                for (int j = 0; j < 8; ++j)
                    acc[i][j] = fmaf(zr[i], wr[j], acc[i][j]);
        }

        // dist = fl(fl(a+b) - 2*dot); ascending k + strict < = first-index tie-break
        #pragma unroll
        for (int i = 0; i < 4; ++i) {
            #pragma unroll
            for (int j = 0; j < 8; ++j) {
                float dist = __fsub_rn(__fadd_rn(av[i], bnd[tx8 + j]), 2.0f * acc[i][j]);
                int k = chunk * 128 + tx8 + j;
                if (dist < best[i]) { best[i] = dist; bidx[i] = k; }
            }
        }
        __syncthreads();   // before restaging wt (and before overlay use on last iter)
    }

    // ---- cross-thread argmin reduction per point ----
    #pragma unroll
    for (int i = 0; i < 4; ++i) {
        redv[tx * 66 + ty4 + i] = best[i];
        redi[tx * 64 + ty4 + i] = bidx[i];
    }
    __syncthreads();

    if (t < 64) {
        float bv = redv[t];
        int bi = redi[t];
        #pragma unroll
        for (int x = 1; x < 16; ++x) {
            float v = redv[x * 66 + t];
            int ii = redi[x * 64 + t];
            if (v < bv || (v == bv && ii < bi)) { bv = v; bi = ii; }
        }
        idxs[t] = bi;
        atomicAdd(&hist[bi], 1);
        out[OFF_CB + (size_t)blk * 64 + t] = (float)bi;
        // gather winner row into zqt[d][p] (float4 per row chunk)
        const float4* wr4 = (const float4*)(wg + (size_t)bi * 64);
        #pragma unroll
        for (int q = 0; q < 16; ++q) {
            float4 v = wr4[q];
            zqt[(4 * q + 0) * 64 + t] = v.x;
            zqt[(4 * q + 1) * 64 + t] = v.y;
            zqt[(4 * q + 2) * 64 + t] = v.z;
            zqt[(4 * q + 3) * 64 + t] = v.w;
        }
    }
    __syncthreads();

    // ---- encodings: 64 rows x 512 one-hot floats, fully coalesced float4 ----
    {
        float4* enc = (float4*)(out + OFF_ENC + (size_t)blk * 64 * NK);
        for (int e = t; e < 64 * 128; e += 256) {
            int r = e >> 7, c4 = e & 127;
            int idx = idxs[r];
            float4 v = make_float4(0.f, 0.f, 0.f, 0.f);
            if ((idx >> 2) == c4) ((float*)&v)[idx & 3] = 1.0f;
            enc[(size_t)r * 128 + c4] = v;
        }
    }

    // ---- z_q (straight-through: z + (q - z)) + loss partial ----
    float lsum = 0.f;
    {
        float* zq = out + OFF_ZQ + (size_t)b * 262144 + (size_t)h * 64;
        for (int e = t; e < 4096; e += 256) {
            int p = e & 63, d = e >> 6;
            float zv = zt[d * 64 + p];
            float qv = zqt[d * 64 + p];
            float diff = __fsub_rn(qv, zv);
            lsum = __fadd_rn(lsum, __fmul_rn(diff, diff));
            zq[(size_t)d * 4096 + p] = __fadd_rn(zv, diff);
        }
    }
    rsum[t] = lsum;
    __syncthreads();
    for (int s = 128; s > 0; s >>= 1) {
        if (t < s) rsum[t] += rsum[t + s];
        __syncthreads();
    }
    if (t == 0) atomicAdd(lossAcc, (double)rsum[0]);
}

__global__ __launch_bounds__(512) void vq_finalize(const int* __restrict__ hist,
                                                   const double* __restrict__ lossAcc,
                                                   float* __restrict__ out) {
    __shared__ float sh[512];
    const int t = threadIdx.x;
    float p = (float)hist[t] / (float)NPTS;   // exact: /2^17
    sh[t] = __fmul_rn(p, logf(__fadd_rn(p, 1e-10f)));
    __syncthreads();
    for (int s = 256; s > 0; s >>= 1) {
        if (t < s) sh[t] += sh[t + s];
        __syncthreads();
    }
    if (t == 0) {
        float m = (float)(*lossAcc / (double)NELEM);
        out[OFF_LOSS] = __fadd_rn(m, __fmul_rn(0.25f, m));
        out[OFF_PERP] = expf(-sh[0]);
    }
}

extern "C" void kernel_launch(void* const* d_in, const int* in_sizes, int n_in,
                              void* d_out, int out_size, void* d_ws, size_t ws_size,
                              hipStream_t stream) {
    const float* z = (const float*)d_in[0];
    const float* w = (const float*)d_in[1];
    float* out = (float*)d_out;
    int* hist = (int*)d_ws;
    double* lossAcc = (double*)((char*)d_ws + 2048);

    hipMemsetAsync(d_ws, 0, 4096, stream);
    vq_main<<<2048, 256, 0, stream>>>(z, w, out, hist, lossAcc);
    vq_finalize<<<1, 512, 0, stream>>>(hist, lossAcc, out);
}

// Round 3
// 467.814 us; speedup vs baseline: 1.0091x; 1.0091x over previous
//
#include <hip/hip_runtime.h>
#include <math.h>

#define NK 512                      // N_EMB
#define NPTS (32*64*64)             // 131072 points
#define NELEM (32*64*64*64)         // 8388608 elements of z

typedef float nvf4 __attribute__((ext_vector_type(4)));   // native vec4 for nontemporal

// flat d_out offsets (return order: loss, z_q, perplexity, encodings, codebook)
#define OFF_LOSS 0
#define OFF_ZQ   1
#define OFF_PERP (1 + NELEM)
#define OFF_ENC  (2 + NELEM)
#define OFF_CB   (2 + NELEM + (size_t)NPTS * NK)

// ws layout: [0,2048) hist int[512] | [2048,2056) lossAcc double |
//            [4096, +128KB) wT f32[64][512] | then bnd f32[512]

// ---- prep: wT[d][k] = w[k][d]; bnd[k] = sum_d w[k][d]^2 (sequential d) ----
__global__ __launch_bounds__(256) void vq_prep(const float* __restrict__ wg,
                                               float* __restrict__ wT,
                                               float* __restrict__ bnd) {
    __shared__ float tl[64 * 65];
    const int t = threadIdx.x;
    const int kbase = blockIdx.x * 64;          // 8 blocks x 64 codes
    // coalesced read -> padded LDS
    #pragma unroll
    for (int it = 0; it < 16; ++it) {
        int i = it * 256 + t;
        int k = i >> 6, d = i & 63;
        tl[k * 65 + d] = wg[(size_t)(kbase + k) * 64 + d];
    }
    __syncthreads();
    // coalesced transposed write
    #pragma unroll
    for (int it = 0; it < 16; ++it) {
        int j = it * 256 + t;
        int d = j >> 6, kk = j & 63;
        wT[(size_t)d * 512 + kbase + kk] = tl[kk * 65 + d];
    }
    if (t < 64) {
        float s = 0.f;
        #pragma unroll 4
        for (int d = 0; d < 64; ++d) {
            float v = tl[t * 65 + d];
            s = __fadd_rn(s, __fmul_rn(v, v));
        }
        bnd[kbase + t] = s;
    }
}

__global__ __launch_bounds__(256) void vq_main(const float* __restrict__ zg,
                                               const float* __restrict__ wg,
                                               const float* __restrict__ wT,
                                               const float* __restrict__ bndg,
                                               float* __restrict__ out,
                                               int* __restrict__ hist,
                                               double* __restrict__ lossAcc) {
    const int t = threadIdx.x;
    const int blk = blockIdx.x;          // 2048 blocks = (b,h)
    const int b = blk >> 6;
    const int h = blk & 63;

    __shared__ __align__(16) float zt[64 * 64];    // zt[d][p]
    __shared__ __align__(16) float wt[64 * 128];   // wt[d][k] chunk (no pad needed)
    __shared__ float aRow[64];
    __shared__ int   idxs[64];
    __shared__ float wsum[4];

    // overlays into wt region (valid after final chunk barrier)
    float* zqt  = wt;                          // [64][64]
    float* redv = wt + 4096;                   // [16][68]
    int*   redi = (int*)(wt + 4096 + 16 * 68); // [16][64]

    const float4* wT4 = (const float4*)wT;
    float4* wt4 = (float4*)wt;
    const int d0 = t >> 5, c4 = t & 31;        // staging mapping (8 rows apart)

    // issue chunk-0 prefetch early (overlaps zt staging)
    float4 pf[8];
    #pragma unroll
    for (int s = 0; s < 8; ++s)
        pf[s] = wT4[(size_t)(d0 + s * 8) * 128 + c4];

    // ---- stage z tile: zt[c][w] = z[b,c,h,w] (contiguous LDS writes) ----
    {
        const int w = t & 63;
        const int c0 = t >> 6;
        const size_t base = (size_t)b * 262144 + (size_t)h * 64;
        #pragma unroll
        for (int c = c0; c < 64; c += 4)
            zt[c * 64 + w] = zg[base + (size_t)c * 4096 + w];
    }
    __syncthreads();

    // ---- a_p = sum_d z^2 (sequential d, mul+add — matches reference) ----
    if (t < 64) {
        float s = 0.f;
        for (int d = 0; d < 64; ++d) {
            float v = zt[d * 64 + t];
            s = __fadd_rn(s, __fmul_rn(v, v));
        }
        aRow[t] = s;
    }
    __syncthreads();

    const int tx = t & 15;     // point group: p = tx*4 + i
    const int ty = t >> 4;     // code group:  k = chunk*128 + ty*8 + j
    const int p0 = tx * 4;
    const int ty8 = ty * 8;

    float av[4];
    #pragma unroll
    for (int i = 0; i < 4; ++i) av[i] = aRow[p0 + i];

    float best[4];
    int bidx[4];
    #pragma unroll
    for (int i = 0; i < 4; ++i) { best[i] = INFINITY; bidx[i] = 0; }

    for (int c = 0; c < 4; ++c) {
        if (c) __syncthreads();   // WAR: previous chunk fully read

        // contiguous ds_write of the prefetched chunk
        #pragma unroll
        for (int s = 0; s < 8; ++s)
            wt4[(d0 + s * 8) * 32 + c4] = pf[s];

        // prefetch next chunk (lands during compute)
        if (c < 3) {
            #pragma unroll
            for (int s = 0; s < 8; ++s)
                pf[s] = wT4[(size_t)(d0 + s * 8) * 128 + (c + 1) * 32 + c4];
        }

        // code norms for this thread's 8 codes (L1/L2-cached broadcast)
        float bn[8];
        {
            const float4* bp = (const float4*)(bndg + c * 128 + ty8);
            float4 b0 = bp[0], b1 = bp[1];
            bn[0] = b0.x; bn[1] = b0.y; bn[2] = b0.z; bn[3] = b0.w;
            bn[4] = b1.x; bn[5] = b1.y; bn[6] = b1.z; bn[7] = b1.w;
        }
        __syncthreads();          // RAW: wt staged

        // ---- register-tiled dots: 4 points x 8 codes, conflict-free LDS ----
        float acc[4][8];
        #pragma unroll
        for (int i = 0; i < 4; ++i)
            #pragma unroll
            for (int j = 0; j < 8; ++j) acc[i][j] = 0.f;

        const float* ztp = zt + p0;
        const float* wtp = wt + ty8;
        #pragma unroll 4
        for (int d = 0; d < 64; ++d) {
            const float4 zv = *(const float4*)(ztp + d * 64);
            const float4 w0 = *(const float4*)(wtp + d * 128);
            const float4 w1 = *(const float4*)(wtp + d * 128 + 4);
            const float zr[4] = {zv.x, zv.y, zv.z, zv.w};
            const float wr[8] = {w0.x, w0.y, w0.z, w0.w, w1.x, w1.y, w1.z, w1.w};
            #pragma unroll
            for (int i = 0; i < 4; ++i)
                #pragma unroll
                for (int j = 0; j < 8; ++j)
                    acc[i][j] = fmaf(zr[i], wr[j], acc[i][j]);
        }

        // dist = fl(fl(a+b) - 2*dot); ascending k + strict < = first-index
        #pragma unroll
        for (int i = 0; i < 4; ++i) {
            #pragma unroll
            for (int j = 0; j < 8; ++j) {
                float dist = __fsub_rn(__fadd_rn(av[i], bn[j]), 2.0f * acc[i][j]);
                int k = c * 128 + ty8 + j;
                if (dist < best[i]) { best[i] = dist; bidx[i] = k; }
            }
        }
    }
    __syncthreads();   // before overlay reuse of wt

    // ---- cross-thread argmin (index tie-break => global first-index) ----
    #pragma unroll
    for (int i = 0; i < 4; ++i) {
        redv[ty * 68 + p0 + i] = best[i];
        redi[ty * 64 + p0 + i] = bidx[i];
    }
    __syncthreads();

    if (t < 64) {
        float bv = redv[t];
        int bi = redi[t];
        #pragma unroll
        for (int x = 1; x < 16; ++x) {
            float v = redv[x * 68 + t];
            int ii = redi[x * 64 + t];
            if (v < bv || (v == bv && ii < bi)) { bv = v; bi = ii; }
        }
        idxs[t] = bi;
        atomicAdd(&hist[bi], 1);
        out[OFF_CB + (size_t)blk * 64 + t] = (float)bi;
        // gather winner row into zqt[d][p]
        const float4* wr4 = (const float4*)(wg + (size_t)bi * 64);
        #pragma unroll
        for (int q = 0; q < 16; ++q) {
            float4 v = wr4[q];
            zqt[(4 * q + 0) * 64 + t] = v.x;
            zqt[(4 * q + 1) * 64 + t] = v.y;
            zqt[(4 * q + 2) * 64 + t] = v.z;
            zqt[(4 * q + 3) * 64 + t] = v.w;
        }
    }
    __syncthreads();

    // ---- encodings: one-hot rows, coalesced nontemporal float4 ----
    {
        nvf4* enc = (nvf4*)(out + OFF_ENC + (size_t)blk * 64 * NK);
        #pragma unroll
        for (int it = 0; it < 32; ++it) {
            int e = it * 256 + t;
            int r = e >> 7, cc = e & 127;
            int idx = idxs[r];
            nvf4 v = (nvf4)(0.f);
            if ((idx >> 2) == cc) v[idx & 3] = 1.0f;
            __builtin_nontemporal_store(v, &enc[(size_t)r * 128 + cc]);
        }
    }

    // ---- z_q (straight-through) + loss partial, vectorized ----
    float lsum = 0.f;
    {
        float* zq = out + OFF_ZQ + (size_t)b * 262144 + (size_t)h * 64;
        #pragma unroll
        for (int it = 0; it < 4; ++it) {
            int f = it * 256 + t;            // 1024 float4s
            int d = f >> 4, pp = (f & 15) * 4;
            float4 zv = *(const float4*)(zt + d * 64 + pp);
            float4 qv = *(const float4*)(zqt + d * 64 + pp);
            nvf4 o;
            float dx = __fsub_rn(qv.x, zv.x); lsum = __fadd_rn(lsum, __fmul_rn(dx, dx)); o[0] = __fadd_rn(zv.x, dx);
            float dy = __fsub_rn(qv.y, zv.y); lsum = __fadd_rn(lsum, __fmul_rn(dy, dy)); o[1] = __fadd_rn(zv.y, dy);
            float dz = __fsub_rn(qv.z, zv.z); lsum = __fadd_rn(lsum, __fmul_rn(dz, dz)); o[2] = __fadd_rn(zv.z, dz);
            float dw = __fsub_rn(qv.w, zv.w); lsum = __fadd_rn(lsum, __fmul_rn(dw, dw)); o[3] = __fadd_rn(zv.w, dw);
            __builtin_nontemporal_store(o, (nvf4*)(zq + (size_t)d * 4096 + pp));
        }
    }
    #pragma unroll
    for (int off = 32; off > 0; off >>= 1)
        lsum += __shfl_down(lsum, off);
    if ((t & 63) == 0) wsum[t >> 6] = lsum;
    __syncthreads();
    if (t == 0) {
        float tot = (wsum[0] + wsum[1]) + (wsum[2] + wsum[3]);
        atomicAdd(lossAcc, (double)tot);
    }
}

__global__ __launch_bounds__(512) void vq_finalize(const int* __restrict__ hist,
                                                   const double* __restrict__ lossAcc,
                                                   float* __restrict__ out) {
    __shared__ float sh[512];
    const int t = threadIdx.x;
    float p = (float)hist[t] / (float)NPTS;   // exact: /2^17
    sh[t] = __fmul_rn(p, logf(__fadd_rn(p, 1e-10f)));
    __syncthreads();
    for (int s = 256; s > 0; s >>= 1) {
        if (t < s) sh[t] += sh[t + s];
        __syncthreads();
    }
    if (t == 0) {
        float m = (float)(*lossAcc / (double)NELEM);
        out[OFF_LOSS] = __fadd_rn(m, __fmul_rn(0.25f, m));
        out[OFF_PERP] = expf(-sh[0]);
    }
}

extern "C" void kernel_launch(void* const* d_in, const int* in_sizes, int n_in,
                              void* d_out, int out_size, void* d_ws, size_t ws_size,
                              hipStream_t stream) {
    const float* z = (const float*)d_in[0];
    const float* w = (const float*)d_in[1];
    float* out = (float*)d_out;
    int* hist = (int*)d_ws;
    double* lossAcc = (double*)((char*)d_ws + 2048);
    float* wT = (float*)((char*)d_ws + 4096);
    float* bnd = wT + 64 * 512;

    (void)hipMemsetAsync(d_ws, 0, 4096, stream);
    vq_prep<<<8, 256, 0, stream>>>(w, wT, bnd);
    vq_main<<<2048, 256, 0, stream>>>(z, w, wT, bnd, out, hist, lossAcc);
    vq_finalize<<<1, 512, 0, stream>>>(hist, lossAcc, out);
}

// Round 5
// 460.725 us; speedup vs baseline: 1.0247x; 1.0154x over previous
//
#include <hip/hip_runtime.h>
#include <math.h>

#define NK 512                      // N_EMB
#define NPTS (32*64*64)             // 131072 points
#define NELEM (32*64*64*64)         // 8388608 elements of z

// flat d_out offsets (return order: loss, z_q, perplexity, encodings, codebook)
#define OFF_LOSS 0
#define OFF_ZQ   1
#define OFF_PERP (1 + NELEM)
#define OFF_ENC  (2 + NELEM)
#define OFF_CB   (2 + NELEM + (size_t)NPTS * NK)

// ws layout: [0,2048) hist int[512] | [2048,2056) lossAcc double |
//            [4096, +128KB) wT f32[64][512] | then bnd f32[512]

// ---- prep: wT[d][k] = w[k][d]; bnd[k] = sum_d w[k][d]^2 (sequential d) ----
__global__ __launch_bounds__(256) void vq_prep(const float* __restrict__ wg,
                                               float* __restrict__ wT,
                                               float* __restrict__ bnd) {
    __shared__ float tl[64 * 65];
    const int t = threadIdx.x;
    const int kbase = blockIdx.x * 64;          // 8 blocks x 64 codes
    #pragma unroll
    for (int it = 0; it < 16; ++it) {
        int i = it * 256 + t;
        int k = i >> 6, d = i & 63;
        tl[k * 65 + d] = wg[(size_t)(kbase + k) * 64 + d];
    }
    __syncthreads();
    #pragma unroll
    for (int it = 0; it < 16; ++it) {
        int j = it * 256 + t;
        int d = j >> 6, kk = j & 63;
        wT[(size_t)d * 512 + kbase + kk] = tl[kk * 65 + d];
    }
    if (t < 64) {
        float s = 0.f;
        #pragma unroll 4
        for (int d = 0; d < 64; ++d) {
            float v = tl[t * 65 + d];
            s = __fadd_rn(s, __fmul_rn(v, v));
        }
        bnd[kbase + t] = s;
    }
}

// tile: block = 64 points (one b,h row); 2 chunks x 256 codes.
// 256 threads = 8 point-groups (P=8) x 32 code-groups (C=8) — exact cover.
// 64 B LDS/lane/d per 64 FMA -> 50% VALU ceiling (LDS-return-bound).
__global__ __launch_bounds__(256, 2) void vq_main(const float* __restrict__ zg,
                                                  const float* __restrict__ wg,
                                                  const float* __restrict__ wT,
                                                  const float* __restrict__ bndg,
                                                  float* __restrict__ out,
                                                  int* __restrict__ hist,
                                                  double* __restrict__ lossAcc) {
    const int t = threadIdx.x;
    const int blk = blockIdx.x;          // 2048 blocks = (b,h)
    const int b = blk >> 6;
    const int h = blk & 63;

    __shared__ __align__(16) float zt[64 * 64];    // zt[d][p]   (16 KB)
    __shared__ __align__(16) float wt[64 * 256];   // wt[d][k]   (64 KB) + overlays

    // overlays inside wt
    float* aRow = wt;                          // [64] — dead before chunk-0 staging
    float* redv = wt;                          // [32][64] — after last compute barrier
    int*   redi = (int*)(wt + 2048);           // [32][64]
    float* zqt  = wt + 4096;                   // [64][64]
    int*   idxs = (int*)(wt + 8192);           // [64]
    float* wsum = wt + 8256;                   // [4]

    // ---- stage z tile: zt[c][w] = z[b,c,h,w] ----
    {
        const int w = t & 63;
        const int c0 = t >> 6;
        const size_t base = (size_t)b * 262144 + (size_t)h * 64;
        #pragma unroll
        for (int c = c0; c < 64; c += 4)
            zt[c * 64 + w] = zg[base + (size_t)c * 4096 + w];
    }
    __syncthreads();

    // ---- a_p = sum_d z^2 (sequential d, mul+add — matches reference) ----
    if (t < 64) {
        float s = 0.f;
        for (int d = 0; d < 64; ++d) {
            float v = zt[d * 64 + t];
            s = __fadd_rn(s, __fmul_rn(v, v));
        }
        aRow[t] = s;
    }
    __syncthreads();

    const int tx = t & 7;      // point group: p = tx*8 + i   (i < 8)
    const int ty = t >> 3;     // code group:  k = c*256 + ty*8 + j  (j < 8)
    const int p0 = tx * 8;
    const int k0 = ty * 8;

    float av[8];
    {
        float4 a0 = *(const float4*)(aRow + p0);
        float4 a1 = *(const float4*)(aRow + p0 + 4);
        av[0] = a0.x; av[1] = a0.y; av[2] = a0.z; av[3] = a0.w;
        av[4] = a1.x; av[5] = a1.y; av[6] = a1.z; av[7] = a1.w;
    }
    __syncthreads();   // av consumed -> aRow region may be overwritten by wt staging

    float best[8];
    int bidx[8];
    #pragma unroll
    for (int i = 0; i < 8; ++i) { best[i] = INFINITY; bidx[i] = 0; }

    const float4* wT4 = (const float4*)wT;     // row stride 128 float4s
    float4* wt4 = (float4*)wt;                 // row stride 64 float4s

    for (int c = 0; c < 2; ++c) {
        if (c) __syncthreads();   // WAR: previous chunk fully read

        // stage wt chunk: 64 rows x 256 floats (contiguous, conflict-free)
        #pragma unroll
        for (int it = 0; it < 16; ++it) {
            int i = it * 256 + t;
            int d = i >> 6, c4 = i & 63;
            wt4[d * 64 + c4] = wT4[(size_t)d * 128 + c * 64 + c4];
        }

        // code norms for this thread's 8 codes (global, L1/L2 broadcast)
        float bn[8];
        {
            const float4* bp = (const float4*)(bndg + c * 256 + k0);
            float4 b0 = bp[0], b1 = bp[1];
            bn[0] = b0.x; bn[1] = b0.y; bn[2] = b0.z; bn[3] = b0.w;
            bn[4] = b1.x; bn[5] = b1.y; bn[6] = b1.z; bn[7] = b1.w;
        }
        __syncthreads();          // RAW: wt staged

        float acc[8][8];
        #pragma unroll
        for (int i = 0; i < 8; ++i)
            #pragma unroll
            for (int j = 0; j < 8; ++j) acc[i][j] = 0.f;

        const float* ztp = zt + p0;
        const float* wtp = wt + k0;
        #pragma unroll 4
        for (int d = 0; d < 64; ++d) {
            float4 z0 = *(const float4*)(ztp + d * 64);
            float4 z1 = *(const float4*)(ztp + d * 64 + 4);
            float4 w0 = *(const float4*)(wtp + d * 256);
            float4 w1 = *(const float4*)(wtp + d * 256 + 4);
            const float zr[8] = {z0.x, z0.y, z0.z, z0.w, z1.x, z1.y, z1.z, z1.w};
            const float wr[8] = {w0.x, w0.y, w0.z, w0.w, w1.x, w1.y, w1.z, w1.w};
            #pragma unroll
            for (int i = 0; i < 8; ++i)
                #pragma unroll
                for (int j = 0; j < 8; ++j)
                    acc[i][j] = fmaf(zr[i], wr[j], acc[i][j]);
        }

        // dist = fl(fl(a+b) - 2*dot); ascending k + strict < = first-index
        #pragma unroll
        for (int i = 0; i < 8; ++i) {
            #pragma unroll
            for (int j = 0; j < 8; ++j) {
                float dist = __fsub_rn(__fadd_rn(av[i], bn[j]), 2.0f * acc[i][j]);
                int k = c * 256 + k0 + j;
                if (dist < best[i]) { best[i] = dist; bidx[i] = k; }
            }
        }
    }
    __syncthreads();   // before overlay reuse of wt

    // ---- cross-thread argmin (index tie-break => global first-index) ----
    #pragma unroll
    for (int i = 0; i < 8; ++i) {
        redv[ty * 64 + p0 + i] = best[i];
        redi[ty * 64 + p0 + i] = bidx[i];
    }
    __syncthreads();

    if (t < 64) {
        float bv = redv[t];
        int bi = redi[t];
        #pragma unroll
        for (int x = 1; x < 32; ++x) {
            float v = redv[x * 64 + t];
            int ii = redi[x * 64 + t];
            if (v < bv || (v == bv && ii < bi)) { bv = v; bi = ii; }
        }
        idxs[t] = bi;
        atomicAdd(&hist[bi], 1);
        out[OFF_CB + (size_t)blk * 64 + t] = (float)bi;
        // gather winner row into zqt[d][p]
        const float4* wr4 = (const float4*)(wg + (size_t)bi * 64);
        #pragma unroll
        for (int q = 0; q < 16; ++q) {
            float4 v = wr4[q];
            zqt[(4 * q + 0) * 64 + t] = v.x;
            zqt[(4 * q + 1) * 64 + t] = v.y;
            zqt[(4 * q + 2) * 64 + t] = v.z;
            zqt[(4 * q + 3) * 64 + t] = v.w;
        }
    }
    __syncthreads();

    // ---- encodings: one-hot rows, coalesced float4 (plain stores) ----
    {
        float4* enc = (float4*)(out + OFF_ENC + (size_t)blk * 64 * NK);
        #pragma unroll
        for (int it = 0; it < 32; ++it) {
            int e = it * 256 + t;
            int r = e >> 7, cc = e & 127;
            int idx = idxs[r];
            float4 v = make_float4(0.f, 0.f, 0.f, 0.f);
            if ((idx >> 2) == cc) ((float*)&v)[idx & 3] = 1.0f;
            enc[(size_t)r * 128 + cc] = v;
        }
    }

    // ---- z_q (straight-through) + loss partial, vectorized ----
    float lsum = 0.f;
    {
        float* zq = out + OFF_ZQ + (size_t)b * 262144 + (size_t)h * 64;
        #pragma unroll
        for (int it = 0; it < 4; ++it) {
            int f = it * 256 + t;            // 1024 float4s
            int d = f >> 4, pp = (f & 15) * 4;
            float4 zv = *(const float4*)(zt + d * 64 + pp);
            float4 qv = *(const float4*)(zqt + d * 64 + pp);
            float4 o;
            float dx = __fsub_rn(qv.x, zv.x); lsum = __fadd_rn(lsum, __fmul_rn(dx, dx)); o.x = __fadd_rn(zv.x, dx);
            float dy = __fsub_rn(qv.y, zv.y); lsum = __fadd_rn(lsum, __fmul_rn(dy, dy)); o.y = __fadd_rn(zv.y, dy);
            float dz = __fsub_rn(qv.z, zv.z); lsum = __fadd_rn(lsum, __fmul_rn(dz, dz)); o.z = __fadd_rn(zv.z, dz);
            float dw = __fsub_rn(qv.w, zv.w); lsum = __fadd_rn(lsum, __fmul_rn(dw, dw)); o.w = __fadd_rn(zv.w, dw);
            *(float4*)(zq + (size_t)d * 4096 + pp) = o;
        }
    }
    #pragma unroll
    for (int off = 32; off > 0; off >>= 1)
        lsum += __shfl_down(lsum, off);
    if ((t & 63) == 0) wsum[t >> 6] = lsum;
    __syncthreads();
    if (t == 0) {
        float tot = (wsum[0] + wsum[1]) + (wsum[2] + wsum[3]);
        atomicAdd(lossAcc, (double)tot);
    }
}

__global__ __launch_bounds__(512) void vq_finalize(const int* __restrict__ hist,
                                                   const double* __restrict__ lossAcc,
                                                   float* __restrict__ out) {
    __shared__ float sh[512];
    const int t = threadIdx.x;
    float p = (float)hist[t] / (float)NPTS;   // exact: /2^17
    sh[t] = __fmul_rn(p, logf(__fadd_rn(p, 1e-10f)));
    __syncthreads();
    for (int s = 256; s > 0; s >>= 1) {
        if (t < s) sh[t] += sh[t + s];
        __syncthreads();
    }
    if (t == 0) {
        float m = (float)(*lossAcc / (double)NELEM);
        out[OFF_LOSS] = __fadd_rn(m, __fmul_rn(0.25f, m));
        out[OFF_PERP] = expf(-sh[0]);
    }
}

extern "C" void kernel_launch(void* const* d_in, const int* in_sizes, int n_in,
                              void* d_out, int out_size, void* d_ws, size_t ws_size,
                              hipStream_t stream) {
    const float* z = (const float*)d_in[0];
    const float* w = (const float*)d_in[1];
    float* out = (float*)d_out;
    int* hist = (int*)d_ws;
    double* lossAcc = (double*)((char*)d_ws + 2048);
    float* wT = (float*)((char*)d_ws + 4096);
    float* bnd = wT + 64 * 512;

    (void)hipMemsetAsync(d_ws, 0, 4096, stream);
    vq_prep<<<8, 256, 0, stream>>>(w, wT, bnd);
    vq_main<<<2048, 256, 0, stream>>>(z, w, wT, bnd, out, hist, lossAcc);
    vq_finalize<<<1, 512, 0, stream>>>(hist, lossAcc, out);
}